// Round 1
// baseline (49.582 us; speedup 1.0000x reference)
//
#include <hip/hip_runtime.h>
#include <math.h>

#define DD 512
#define BB 128
#define MM 1024
#define MARGIN 9.0f
#define EPSF 1e-6f
#define SPLIT 8

// ---------------- Kernel A: transform head rows ----------------
// grid = B blocks, block = 64 threads (1 wave). Each lane owns 8 elems.
__global__ __launch_bounds__(64) void head_transform_kernel(
    const int* __restrict__ u_idx,
    const int* __restrict__ r_idx,
    const float* __restrict__ emb,
    const float* __restrict__ rrot,
    const float* __restrict__ rcen,
    const float* __restrict__ rtrans,
    float* __restrict__ head_out) {
  const int b = blockIdx.x;
  const int lane = threadIdx.x;  // 0..63
  const int u = u_idx[b];
  const int r = r_idx[b];

  const float4* hrow = (const float4*)(emb + (size_t)u * DD);
  float4 h0 = hrow[2 * lane];
  float4 h1 = hrow[2 * lane + 1];

  // ||head||
  float ss = h0.x * h0.x + h0.y * h0.y + h0.z * h0.z + h0.w * h0.w +
             h1.x * h1.x + h1.y * h1.y + h1.z * h1.z + h1.w * h1.w;
  for (int off = 32; off; off >>= 1) ss += __shfl_xor(ss, off, 64);
  float un = fmaxf(sqrtf(ss), 1e-15f);
  float scale = tanhf(un) / un;  // sqrt_c = 1

  const float4* grow = (const float4*)(rrot + (size_t)r * DD);
  const float4* crow = (const float4*)(rcen + (size_t)r * DD);
  const float4* trow = (const float4*)(rtrans + (size_t)r * DD);
  float4 g0 = grow[2 * lane], g1 = grow[2 * lane + 1];
  float4 c0 = crow[2 * lane], c1 = crow[2 * lane + 1];
  float4 t0 = trow[2 * lane], t1 = trow[2 * lane + 1];

  // x = expmap0(head) + r_center
  float4 x0, x1;
  x0.x = h0.x * scale + c0.x; x0.y = h0.y * scale + c0.y;
  x0.z = h0.z * scale + c0.z; x0.w = h0.w * scale + c0.w;
  x1.x = h1.x * scale + c1.x; x1.y = h1.y * scale + c1.y;
  x1.z = h1.z * scale + c1.z; x1.w = h1.w * scale + c1.w;

  // Givens rotation per consecutive 2-dim pair, then -center +trans +EPS
  float4 o0, o1;
  {
    float gn = fmaxf(sqrtf(g0.x * g0.x + g0.y * g0.y), 1e-15f);
    float cc = g0.x / gn, sn = g0.y / gn;
    o0.x = cc * x0.x - sn * x0.y;
    o0.y = cc * x0.y + sn * x0.x;
  }
  {
    float gn = fmaxf(sqrtf(g0.z * g0.z + g0.w * g0.w), 1e-15f);
    float cc = g0.z / gn, sn = g0.w / gn;
    o0.z = cc * x0.z - sn * x0.w;
    o0.w = cc * x0.w + sn * x0.z;
  }
  {
    float gn = fmaxf(sqrtf(g1.x * g1.x + g1.y * g1.y), 1e-15f);
    float cc = g1.x / gn, sn = g1.y / gn;
    o1.x = cc * x1.x - sn * x1.y;
    o1.y = cc * x1.y + sn * x1.x;
  }
  {
    float gn = fmaxf(sqrtf(g1.z * g1.z + g1.w * g1.w), 1e-15f);
    float cc = g1.z / gn, sn = g1.w / gn;
    o1.z = cc * x1.z - sn * x1.w;
    o1.w = cc * x1.w + sn * x1.z;
  }

  // out = rotated - r_center + r_trans, fold +EPS of pairwise distance
  o0.x = o0.x - c0.x + t0.x + EPSF; o0.y = o0.y - c0.y + t0.y + EPSF;
  o0.z = o0.z - c0.z + t0.z + EPSF; o0.w = o0.w - c0.w + t0.w + EPSF;
  o1.x = o1.x - c1.x + t1.x + EPSF; o1.y = o1.y - c1.y + t1.y + EPSF;
  o1.z = o1.z - c1.z + t1.z + EPSF; o1.w = o1.w - c1.w + t1.w + EPSF;

  float4* orow = (float4*)(head_out + (size_t)b * DD);
  orow[2 * lane] = o0;
  orow[2 * lane + 1] = o1;
}

// ---------------- Kernel B: pairwise distances ----------------
// grid = B*SPLIT blocks, block = 256 threads (4 waves).
// Each wave handles one m per step; 2KB tail row coalesced per wave.
__global__ __launch_bounds__(256) void dist_kernel(
    const int* __restrict__ u_idx,
    const int* __restrict__ v_idx,
    const float* __restrict__ emb,
    const float* __restrict__ bias_head,
    const float* __restrict__ bias_tail,
    const float* __restrict__ head_t,
    float* __restrict__ out) {
  const int b = blockIdx.x / SPLIT;
  const int s = blockIdx.x % SPLIT;
  const int wid = threadIdx.x >> 6;
  const int lane = threadIdx.x & 63;

  const float4* hrow = (const float4*)(head_t + (size_t)b * DD);
  const float4 h0 = hrow[2 * lane];
  const float4 h1 = hrow[2 * lane + 1];
  const float bh = MARGIN + bias_head[u_idx[b]];

  const int m0 = s * (MM / SPLIT);
  const int mend = m0 + (MM / SPLIT);

  // 2x unrolled: two independent gather chains in flight per wave
  for (int m = m0 + wid; m < mend; m += 8) {
    const int ma = m;
    const int mb = m + 4;

    const int va = v_idx[b * MM + ma];
    const int vb = v_idx[b * MM + mb];

    const float4* ta = (const float4*)(emb + (size_t)va * DD);
    const float4* tb = (const float4*)(emb + (size_t)vb * DD);
    float4 a0 = ta[2 * lane], a1 = ta[2 * lane + 1];
    float4 b0 = tb[2 * lane], b1 = tb[2 * lane + 1];

    float d, acca, accb;
    d = h0.x - a0.x; acca = d * d;
    d = h0.y - a0.y; acca += d * d;
    d = h0.z - a0.z; acca += d * d;
    d = h0.w - a0.w; acca += d * d;
    d = h1.x - a1.x; acca += d * d;
    d = h1.y - a1.y; acca += d * d;
    d = h1.z - a1.z; acca += d * d;
    d = h1.w - a1.w; acca += d * d;

    d = h0.x - b0.x; accb = d * d;
    d = h0.y - b0.y; accb += d * d;
    d = h0.z - b0.z; accb += d * d;
    d = h0.w - b0.w; accb += d * d;
    d = h1.x - b1.x; accb += d * d;
    d = h1.y - b1.y; accb += d * d;
    d = h1.z - b1.z; accb += d * d;
    d = h1.w - b1.w; accb += d * d;

    for (int off = 32; off; off >>= 1) {
      acca += __shfl_xor(acca, off, 64);
      accb += __shfl_xor(accb, off, 64);
    }

    if (lane == 0) {
      out[b * MM + ma] = bh - sqrtf(acca) + bias_tail[va];
      out[b * MM + mb] = bh - sqrtf(accb) + bias_tail[vb];
    }
  }
}

extern "C" void kernel_launch(void* const* d_in, const int* in_sizes, int n_in,
                              void* d_out, int out_size, void* d_ws, size_t ws_size,
                              hipStream_t stream) {
  const int* u_idx = (const int*)d_in[0];
  const int* r_idx = (const int*)d_in[1];
  const int* v_idx = (const int*)d_in[2];
  const float* emb = (const float*)d_in[3];
  const float* rrot = (const float*)d_in[4];
  const float* rcen = (const float*)d_in[5];
  const float* rtrans = (const float*)d_in[6];
  const float* bias_head = (const float*)d_in[7];
  const float* bias_tail = (const float*)d_in[8];
  float* out = (float*)d_out;
  float* head_t = (float*)d_ws;  // B*D floats = 256 KB

  head_transform_kernel<<<BB, 64, 0, stream>>>(u_idx, r_idx, emb, rrot, rcen,
                                               rtrans, head_t);
  dist_kernel<<<BB * SPLIT, 256, 0, stream>>>(u_idx, v_idx, emb, bias_head,
                                              bias_tail, head_t, out);
}

// Round 2
// 47.769 us; speedup vs baseline: 1.0380x; 1.0380x over previous
//
#include <hip/hip_runtime.h>
#include <math.h>

#define DD 512
#define BB 128
#define MM 1024
#define MARGIN 9.0f
#define EPSF 1e-6f
#define SPLIT 16  // blocks per head row; each block covers MM/SPLIT = 64 m's

// One fused kernel. grid = B*SPLIT blocks x 256 threads (4 waves).
// Each wave: recompute transformed head (cheap, L2-hot), then 16 m's as
// 4 iterations x 4 independent gather chains. Lane i owns row floats
// [8i, 8i+8) -> two float4 loads, fully coalesced 2KB per row per wave.
__global__ __launch_bounds__(256) void roth_fused_kernel(
    const int* __restrict__ u_idx,
    const int* __restrict__ r_idx,
    const int* __restrict__ v_idx,
    const float* __restrict__ emb,
    const float* __restrict__ rrot,
    const float* __restrict__ rcen,
    const float* __restrict__ rtrans,
    const float* __restrict__ bias_head,
    const float* __restrict__ bias_tail,
    float* __restrict__ out) {
  const int b = blockIdx.x / SPLIT;
  const int s = blockIdx.x % SPLIT;
  const int wid = threadIdx.x >> 6;
  const int lane = threadIdx.x & 63;
  const int u = u_idx[b];
  const int r = r_idx[b];

  // ---------------- head transform (redundant per wave; rows are L2-hot) ---
  const float4* hrow = (const float4*)(emb + (size_t)u * DD);
  float4 hh0 = hrow[2 * lane];
  float4 hh1 = hrow[2 * lane + 1];

  float ss = hh0.x * hh0.x + hh0.y * hh0.y + hh0.z * hh0.z + hh0.w * hh0.w +
             hh1.x * hh1.x + hh1.y * hh1.y + hh1.z * hh1.z + hh1.w * hh1.w;
  for (int off = 32; off; off >>= 1) ss += __shfl_xor(ss, off, 64);
  float un = fmaxf(sqrtf(ss), 1e-15f);
  float scale = tanhf(un) / un;  // sqrt_c = 1

  const float4* grow = (const float4*)(rrot + (size_t)r * DD);
  const float4* crow = (const float4*)(rcen + (size_t)r * DD);
  const float4* trow = (const float4*)(rtrans + (size_t)r * DD);
  float4 g0 = grow[2 * lane], g1 = grow[2 * lane + 1];
  float4 c0 = crow[2 * lane], c1 = crow[2 * lane + 1];
  float4 t0 = trow[2 * lane], t1 = trow[2 * lane + 1];

  float4 x0, x1;
  x0.x = hh0.x * scale + c0.x; x0.y = hh0.y * scale + c0.y;
  x0.z = hh0.z * scale + c0.z; x0.w = hh0.w * scale + c0.w;
  x1.x = hh1.x * scale + c1.x; x1.y = hh1.y * scale + c1.y;
  x1.z = hh1.z * scale + c1.z; x1.w = hh1.w * scale + c1.w;

  float4 h0, h1;  // transformed head (+EPS folded)
  {
    float gn = fmaxf(sqrtf(g0.x * g0.x + g0.y * g0.y), 1e-15f);
    float cc = g0.x / gn, sn = g0.y / gn;
    h0.x = cc * x0.x - sn * x0.y;
    h0.y = cc * x0.y + sn * x0.x;
  }
  {
    float gn = fmaxf(sqrtf(g0.z * g0.z + g0.w * g0.w), 1e-15f);
    float cc = g0.z / gn, sn = g0.w / gn;
    h0.z = cc * x0.z - sn * x0.w;
    h0.w = cc * x0.w + sn * x0.z;
  }
  {
    float gn = fmaxf(sqrtf(g1.x * g1.x + g1.y * g1.y), 1e-15f);
    float cc = g1.x / gn, sn = g1.y / gn;
    h1.x = cc * x1.x - sn * x1.y;
    h1.y = cc * x1.y + sn * x1.x;
  }
  {
    float gn = fmaxf(sqrtf(g1.z * g1.z + g1.w * g1.w), 1e-15f);
    float cc = g1.z / gn, sn = g1.w / gn;
    h1.z = cc * x1.z - sn * x1.w;
    h1.w = cc * x1.w + sn * x1.z;
  }
  h0.x = h0.x - c0.x + t0.x + EPSF; h0.y = h0.y - c0.y + t0.y + EPSF;
  h0.z = h0.z - c0.z + t0.z + EPSF; h0.w = h0.w - c0.w + t0.w + EPSF;
  h1.x = h1.x - c1.x + t1.x + EPSF; h1.y = h1.y - c1.y + t1.y + EPSF;
  h1.z = h1.z - c1.z + t1.z + EPSF; h1.w = h1.w - c1.w + t1.w + EPSF;

  const float bh = MARGIN + bias_head[u];

  // ---------------- pairwise distances: 16 m's per wave ----------------
  const int mbase = s * (MM / SPLIT) + wid * 16;
  const float* outrow = 0;  // silence unused warnings path
  (void)outrow;

  // prefetch all 16 indices (wave-uniform broadcast loads)
  const int4* vp = (const int4*)(v_idx + b * MM + mbase);
  int4 iv0 = vp[0], iv1 = vp[1], iv2 = vp[2], iv3 = vp[3];
  int idxs[16] = {iv0.x, iv0.y, iv0.z, iv0.w, iv1.x, iv1.y, iv1.z, iv1.w,
                  iv2.x, iv2.y, iv2.z, iv2.w, iv3.x, iv3.y, iv3.z, iv3.w};

#pragma unroll
  for (int it = 0; it < 4; ++it) {
    const int va = idxs[4 * it + 0];
    const int vb = idxs[4 * it + 1];
    const int vc = idxs[4 * it + 2];
    const int vd = idxs[4 * it + 3];

    const float4* ta = (const float4*)(emb + (size_t)va * DD);
    const float4* tb = (const float4*)(emb + (size_t)vb * DD);
    const float4* tc = (const float4*)(emb + (size_t)vc * DD);
    const float4* td = (const float4*)(emb + (size_t)vd * DD);
    float4 a0 = ta[2 * lane], a1 = ta[2 * lane + 1];
    float4 b0 = tb[2 * lane], b1 = tb[2 * lane + 1];
    float4 cc0 = tc[2 * lane], cc1 = tc[2 * lane + 1];
    float4 d0 = td[2 * lane], d1 = td[2 * lane + 1];

    float d, ra, rb, rc, rd;
    d = h0.x - a0.x; ra = d * d;
    d = h0.y - a0.y; ra += d * d;
    d = h0.z - a0.z; ra += d * d;
    d = h0.w - a0.w; ra += d * d;
    d = h1.x - a1.x; ra += d * d;
    d = h1.y - a1.y; ra += d * d;
    d = h1.z - a1.z; ra += d * d;
    d = h1.w - a1.w; ra += d * d;

    d = h0.x - b0.x; rb = d * d;
    d = h0.y - b0.y; rb += d * d;
    d = h0.z - b0.z; rb += d * d;
    d = h0.w - b0.w; rb += d * d;
    d = h1.x - b1.x; rb += d * d;
    d = h1.y - b1.y; rb += d * d;
    d = h1.z - b1.z; rb += d * d;
    d = h1.w - b1.w; rb += d * d;

    d = h0.x - cc0.x; rc = d * d;
    d = h0.y - cc0.y; rc += d * d;
    d = h0.z - cc0.z; rc += d * d;
    d = h0.w - cc0.w; rc += d * d;
    d = h1.x - cc1.x; rc += d * d;
    d = h1.y - cc1.y; rc += d * d;
    d = h1.z - cc1.z; rc += d * d;
    d = h1.w - cc1.w; rc += d * d;

    d = h0.x - d0.x; rd = d * d;
    d = h0.y - d0.y; rd += d * d;
    d = h0.z - d0.z; rd += d * d;
    d = h0.w - d0.w; rd += d * d;
    d = h1.x - d1.x; rd += d * d;
    d = h1.y - d1.y; rd += d * d;
    d = h1.z - d1.z; rd += d * d;
    d = h1.w - d1.w; rd += d * d;

#pragma unroll
    for (int off = 32; off; off >>= 1) {
      ra += __shfl_xor(ra, off, 64);
      rb += __shfl_xor(rb, off, 64);
      rc += __shfl_xor(rc, off, 64);
      rd += __shfl_xor(rd, off, 64);
    }

    if (lane == 0) {
      float4 o;
      o.x = bh - sqrtf(ra) + bias_tail[va];
      o.y = bh - sqrtf(rb) + bias_tail[vb];
      o.z = bh - sqrtf(rc) + bias_tail[vc];
      o.w = bh - sqrtf(rd) + bias_tail[vd];
      *(float4*)(out + b * MM + mbase + 4 * it) = o;
    }
  }
}

extern "C" void kernel_launch(void* const* d_in, const int* in_sizes, int n_in,
                              void* d_out, int out_size, void* d_ws, size_t ws_size,
                              hipStream_t stream) {
  const int* u_idx = (const int*)d_in[0];
  const int* r_idx = (const int*)d_in[1];
  const int* v_idx = (const int*)d_in[2];
  const float* emb = (const float*)d_in[3];
  const float* rrot = (const float*)d_in[4];
  const float* rcen = (const float*)d_in[5];
  const float* rtrans = (const float*)d_in[6];
  const float* bias_head = (const float*)d_in[7];
  const float* bias_tail = (const float*)d_in[8];
  float* out = (float*)d_out;

  roth_fused_kernel<<<BB * SPLIT, 256, 0, stream>>>(
      u_idx, r_idx, v_idx, emb, rrot, rcen, rtrans, bias_head, bias_tail, out);
}